// Round 7
// baseline (357.529 us; speedup 1.0000x reference)
//
#include <hip/hip_runtime.h>

typedef _Float16 f16;
typedef unsigned int uint;
typedef f16 f16x2 __attribute__((ext_vector_type(2)));
typedef f16 f16x8 __attribute__((ext_vector_type(8)));
typedef __fp16 h16x2 __attribute__((ext_vector_type(2)));
typedef float f32x4 __attribute__((ext_vector_type(4)));

#define Bn 512
#define Ln 128
#define Dn 128
#define Cn 512   // 4 gates * D

__device__ __forceinline__ float fdot2f(uint a, uint b, float c) {
#if __has_builtin(__builtin_amdgcn_fdot2)
  return __builtin_amdgcn_fdot2(__builtin_bit_cast(f16x2, a),
                                __builtin_bit_cast(f16x2, b), c, false);
#else
  f16x2 av = __builtin_bit_cast(f16x2, a), bv = __builtin_bit_cast(f16x2, b);
  return c + (float)av[0] * (float)bv[0] + (float)av[1] * (float)bv[1];
#endif
}

__device__ __forceinline__ uint pk2(float a, float b) {
#if __has_builtin(__builtin_amdgcn_cvt_pkrtz)
  h16x2 v = __builtin_amdgcn_cvt_pkrtz(a, b);
  return __builtin_bit_cast(uint, v);
#else
  f16x2 v; v[0] = (f16)a; v[1] = (f16)b;
  return __builtin_bit_cast(uint, v);
#endif
}

// ---------------- merged: convert (blocks 0..191) + embedding gather (rest) ----------------
// convert: W -> MFMA-fragment-ordered f16 (WhF), R -> transposed f16 (RT)
// embed:   x[b*L+t][d] = emb[ids[b*L+t]][d]  (f32, no LN here)
__global__ __launch_bounds__(256) void k_embed_convert(const int* __restrict__ ids,
                                                       const float* __restrict__ emb,
                                                       const float* __restrict__ Wg,
                                                       const float* __restrict__ Rg,
                                                       float* __restrict__ x,
                                                       f16* __restrict__ WhF,
                                                       f16* __restrict__ RT) {
  if (blockIdx.x < 192) {
    int i = blockIdx.x * 256 + threadIdx.x;
    const int nWfrag = 2 * 4 * 32 * 64;   // 16384 groups of 8 f16
    if (i < nWfrag) {
      int lane = i & 63;
      int ii   = (i >> 6) & 31;
      int kk   = (i >> 11) & 3;
      int l    = i >> 13;
      int c = ii * 16 + (lane & 15);
      int d = kk * 32 + ((lane >> 4) << 3);
      const float* src = Wg + ((size_t)(l * 512 + c) * 128 + d);
      f16* dst = WhF + (size_t)i * 8;
      #pragma unroll
      for (int j = 0; j < 8; ++j) dst[j] = (f16)src[j];
    } else {
      int j = i - nWfrag;  // 32768 = 2*4*4*32*32
      if (j < 32768) {
        int dd = j & 31;
        int e  = (j >> 5) & 31;
        int hh = (j >> 10) & 3;
        int g  = (j >> 12) & 3;
        int l  = j >> 14;
        RT[j] = (f16)Rg[((((l * 4 + g) * 4 + hh) * 32 + dd) * 32) + e];
      }
    }
  } else {
    int g = (blockIdx.x - 192) * 256 + threadIdx.x;   // float4 index
    int row = g >> 5;
    int c4 = g & 31;
    int id = ids[row];
    ((float4*)x)[g] = ((const float4*)emb)[(size_t)id * 32 + c4];
  }
}

// ---------------- fused LayerNorm + GEMM ----------------
// Phase 1: LN 64 rows of x (f32) -> LDS tile (f16, 136-pad).
// Phase 2: MFMA GEMM, A-fragments from LDS, B from fragment-ordered WhF.
// preP[m][d] = packed {i,f,z,o} f16.
__global__ __launch_bounds__(256) void k_gemmln(const float* __restrict__ x,
                                                const f16* __restrict__ WhF,
                                                const float* __restrict__ lw,
                                                const float* __restrict__ lb,
                                                const float* __restrict__ bias,
                                                uint2* __restrict__ preP) {
  __shared__ __align__(16) f16 tile[64 * 136];
  int tid = threadIdx.x;
  int m0base = blockIdx.x * 64;

  // ---- LN phase: 4 threads per row, 32 cols each ----
  {
    int r = tid >> 2, cq = tid & 3;
    const float* xr = x + (size_t)(m0base + r) * Dn + cq * 32;
    float v[32];
    float s1 = 0.f, s2 = 0.f;
    #pragma unroll
    for (int j = 0; j < 8; ++j) {
      float4 f = ((const float4*)xr)[j];
      v[4*j] = f.x; v[4*j+1] = f.y; v[4*j+2] = f.z; v[4*j+3] = f.w;
      s1 += f.x + f.y + f.z + f.w;
      s2 += f.x*f.x + f.y*f.y + f.z*f.z + f.w*f.w;
    }
    s1 += __shfl_xor(s1, 1); s2 += __shfl_xor(s2, 1);
    s1 += __shfl_xor(s1, 2); s2 += __shfl_xor(s2, 2);
    float mu = s1 * (1.f / 128.f);
    float var = s2 * (1.f / 128.f) - mu * mu;
    float rs = rsqrtf(var + 1e-5f);
    f16* trow = &tile[r * 136 + cq * 32];
    const float4* lwv = (const float4*)(lw + cq * 32);
    const float4* lbv = (const float4*)(lb + cq * 32);
    #pragma unroll
    for (int j = 0; j < 8; ++j) {
      float4 wv = lwv[j], bv4 = lbv[j];
      trow[4*j]   = (f16)((v[4*j]   - mu) * rs * wv.x + bv4.x);
      trow[4*j+1] = (f16)((v[4*j+1] - mu) * rs * wv.y + bv4.y);
      trow[4*j+2] = (f16)((v[4*j+2] - mu) * rs * wv.z + bv4.z);
      trow[4*j+3] = (f16)((v[4*j+3] - mu) * rs * wv.w + bv4.w);
    }
  }
  __syncthreads();

  // ---- GEMM phase ----
  int w = tid >> 6;
  int lane = tid & 63;
  int l16 = lane & 15, quad = lane >> 4;
  int m0 = m0base + w * 16;

  float bv[32];
  #pragma unroll
  for (int i = 0; i < 32; ++i) bv[i] = bias[i * 16 + l16];

  f16x8 a[4];
  #pragma unroll
  for (int kk = 0; kk < 4; ++kk)
    a[kk] = *(const f16x8*)&tile[(w * 16 + l16) * 136 + quad * 8 + kk * 32];

  f32x4 acc[32] = {};
  const f16* bbase = WhF + (size_t)lane * 8;
  #pragma unroll
  for (int kk = 0; kk < 4; ++kk) {
    #pragma unroll
    for (int i = 0; i < 32; ++i) {
      f16x8 bf = *(const f16x8*)(bbase + (size_t)(kk * 32 + i) * 512);
      acc[i] = __builtin_amdgcn_mfma_f32_16x16x32_f16(a[kk], bf, acc[i], 0, 0, 0);
    }
  }
  #pragma unroll
  for (int r = 0; r < 4; ++r) {
    int m = m0 + quad * 4 + r;
    #pragma unroll
    for (int i7 = 0; i7 < 8; ++i7) {
      uint2 v;
      v.x = pk2(acc[i7][r]      + bv[i7],      acc[i7 + 8][r]  + bv[i7 + 8]);
      v.y = pk2(acc[i7 + 16][r] + bv[i7 + 16], acc[i7 + 24][r] + bv[i7 + 24]);
      preP[(size_t)m * Dn + i7 * 16 + l16] = v;
    }
  }
}

// ---------------- fused scan: 2 lanes/element, 2 waves/SIMD ----------------
// Block = 1 seq, wave = 1 head group (32 elements x 2 lanes). Lane halves split
// the 32-MAC recurrence dot (16 MACs each); partials combined with one
// __shfl_xor(·,32) round (4 gates + 2 gn-stats). Deferred in-lane groupnorm.
// Wave-local LDS h-exchange, no barriers. grid 512 blocks.
template<int LAST>
__global__ __launch_bounds__(256, 2) void k_scan(const uint2* __restrict__ preP,
                                                 const f16* __restrict__ RT,
                                                 const float* __restrict__ gnw,
                                                 const float* __restrict__ xin,
                                                 float* __restrict__ xout,
                                                 float* __restrict__ pooled) {
  const int w = threadIdx.x >> 6;       // wave = head 0..3
  const int lane = threadIdx.x & 63;
  const int half = lane >> 5;           // j-half of the dot
  const int eo = lane & 31;             // element within head group
  const int b = blockIdx.x;             // seq
  const int head = w;
  const int d = head * 32 + eo;
  const uint one2 = 0x3C003C00u;        // f16 {1.0, 1.0}

  __shared__ __align__(16) f16 hsh[4][32];   // per-wave h exchange (64B)

  // R pairs for (gate, head, out-elem eo), input-dd range of my half
  uint rr[4][8];
  const uint* RT32 = (const uint*)RT;
  #pragma unroll
  for (int g = 0; g < 4; ++g) {
    const uint* p = RT32 + ((g * 4 + head) * 32 + eo) * 16 + half * 8;
    #pragma unroll
    for (int j = 0; j < 8; ++j) rr[g][j] = p[j];
  }
  const float gw = gnw[d];
  hsh[w][eo] = (f16)0.f;   // both halves write same value; wave-local in-order

  const uint2* pp = preP + (size_t)b * Ln * Dn + d;
  const float* xp = xin + (size_t)b * Ln * Dn + d;
  float* xo = xout + (size_t)b * Ln * Dn + d;

  // 8-deep raw-bits prefetch pipeline
  uint2 pb[8]; float xb[8];
  #pragma unroll
  for (int k = 0; k < 8; ++k) { pb[k] = pp[(size_t)k * Dn]; xb[k] = xp[(size_t)k * Dn]; }

  float cc = 0.f, nc = 0.f, mc = 0.f, psum = 0.f;
  float hprev = 0.f, xprev = 0.f;

  #pragma unroll 1
  for (int t = 0; t < Ln; t += 8) {
    #pragma unroll
    for (int k = 0; k < 8; ++k) {
      int tt = t + k;
      uint2 pc = pb[k]; float xc = xb[k];
      int tl = tt + 8;
      if (tl < Ln) {
        pb[k] = pp[(size_t)tl * Dn];
        xb[k] = xp[(size_t)tl * Dn];
      }

      // hu = my half of h(tt-1) for this head group (2x ds_read_b128)
      uint hu[8];
      {
        const uint* hp = (const uint*)&hsh[w][0];
        uint4 qa = *(const uint4*)(hp + half * 8);
        uint4 qb = *(const uint4*)(hp + half * 8 + 4);
        hu[0]=qa.x; hu[1]=qa.y; hu[2]=qa.z; hu[3]=qa.w;
        hu[4]=qb.x; hu[5]=qb.y; hu[6]=qb.z; hu[7]=qb.w;
      }

      // partial stats (for deferred gn of h(tt-1)) + partial recurrence dots
      float s1 = 0.f, s2 = 0.f;
      float a0 = 0.f, a1 = 0.f, a2 = 0.f, a3 = 0.f;
      #pragma unroll
      for (int j = 0; j < 8; ++j) {
        a0 = fdot2f(hu[j], rr[0][j], a0);
        a1 = fdot2f(hu[j], rr[1][j], a1);
        a2 = fdot2f(hu[j], rr[2][j], a2);
        a3 = fdot2f(hu[j], rr[3][j], a3);
        s1 = fdot2f(hu[j], one2, s1);
        s2 = fdot2f(hu[j], hu[j], s2);
      }
      // combine halves
      a0 += __shfl_xor(a0, 32);
      a1 += __shfl_xor(a1, 32);
      a2 += __shfl_xor(a2, 32);
      a3 += __shfl_xor(a3, 32);
      s1 += __shfl_xor(s1, 32);
      s2 += __shfl_xor(s2, 32);

      // deferred groupnorm output of step tt-1
      {
        float mu = s1 * (1.f / 32.f);
        float va = s2 * (1.f / 32.f) - mu * mu;
        float ov = xprev + (hprev - mu) * rsqrtf(va + 1e-5f) * gw;
        if (tt > 0) {
          if (LAST) psum += ov;
          else if (!half) xo[(size_t)(tt - 1) * Dn] = ov;
        }
      }

      f16x2 lo = __builtin_bit_cast(f16x2, pc.x);
      f16x2 hi = __builtin_bit_cast(f16x2, pc.y);
      float it = (float)lo[0] + a0, ft = (float)lo[1] + a1;
      float zt = (float)hi[0] + a2, ot = (float)hi[1] + a3;

      float mn = fmaxf(ft + mc, it);
      float iv = __expf(it - mn);
      float fv = __expf(ft + mc - mn);
      float zc = fminf(fmaxf(zt, -15.f), 15.f);
      float ez = __expf(2.f * zc);
      float tz = (ez - 1.f) * __builtin_amdgcn_rcpf(ez + 1.f);
      float cn = fv * cc + iv * tz;
      float nn = fv * nc + iv;
      float sg = __builtin_amdgcn_rcpf(1.f + __expf(-ot));
      float hn = sg * cn * __builtin_amdgcn_rcpf(nn);
      cc = cn; nc = nn; mc = mn;

      hsh[w][eo] = (f16)hn;   // both halves write identical value
      hprev = hn; xprev = xc;
    }
  }

  // epilogue: groupnorm of step 127
  {
    uint hu[8];
    const uint* hp = (const uint*)&hsh[w][0];
    uint4 qa = *(const uint4*)(hp + half * 8);
    uint4 qb = *(const uint4*)(hp + half * 8 + 4);
    hu[0]=qa.x; hu[1]=qa.y; hu[2]=qa.z; hu[3]=qa.w;
    hu[4]=qb.x; hu[5]=qb.y; hu[6]=qb.z; hu[7]=qb.w;
    float s1 = 0.f, s2 = 0.f;
    #pragma unroll
    for (int j = 0; j < 8; ++j) {
      s1 = fdot2f(hu[j], one2, s1);
      s2 = fdot2f(hu[j], hu[j], s2);
    }
    s1 += __shfl_xor(s1, 32);
    s2 += __shfl_xor(s2, 32);
    float mu = s1 * (1.f / 32.f);
    float va = s2 * (1.f / 32.f) - mu * mu;
    float ov = xprev + (hprev - mu) * rsqrtf(va + 1e-5f) * gw;
    if (LAST) {
      psum += ov;
      if (!half) pooled[b * Dn + d] = psum * (1.f / 128.f);
    } else {
      if (!half) xo[(size_t)(Ln - 1) * Dn] = ov;
    }
  }
}

// ---------------- head: MLP on pooled [512][128] ----------------
__global__ __launch_bounds__(64) void k_head(const float* __restrict__ pooled,
                                             const float* __restrict__ w1,
                                             const float* __restrict__ b1,
                                             const float* __restrict__ w2,
                                             const float* __restrict__ b2,
                                             float* __restrict__ out) {
  int b = blockIdx.x;
  int tid = threadIdx.x;  // 64
  __shared__ float pool[128];
  __shared__ float hid[64];
  pool[tid]      = pooled[b * Dn + tid];
  pool[tid + 64] = pooled[b * Dn + tid + 64];
  __syncthreads();
  {
    float a = b1[tid];
    const float* wr = w1 + (size_t)tid * Dn;
    #pragma unroll 4
    for (int dd = 0; dd < Dn; ++dd) a += pool[dd] * wr[dd];
    hid[tid] = fmaxf(a, 0.f);
  }
  __syncthreads();
  if (tid < 2) {
    float a = b2[tid];
    const float* wr = w2 + tid * 64;
    #pragma unroll 4
    for (int j = 0; j < 64; ++j) a += hid[j] * wr[j];
    out[b * 2 + tid] = a;
  }
}

extern "C" void kernel_launch(void* const* d_in, const int* in_sizes, int n_in,
                              void* d_out, int out_size, void* d_ws, size_t ws_size,
                              hipStream_t stream) {
  const int*   ids  = (const int*)d_in[0];
  const float* emb  = (const float*)d_in[1];
  const float* ln_w = (const float*)d_in[2];
  const float* ln_b = (const float*)d_in[3];
  const float* Wg   = (const float*)d_in[4];
  const float* Rg   = (const float*)d_in[5];
  const float* bg   = (const float*)d_in[6];
  const float* gn_w = (const float*)d_in[7];
  const float* w1   = (const float*)d_in[8];
  const float* b1   = (const float*)d_in[9];
  const float* w2   = (const float*)d_in[10];
  const float* b2   = (const float*)d_in[11];
  float* out = (float*)d_out;

  char* ws = (char*)d_ws;
  float* x     = (float*)ws;                                   // 33,554,432 B
  uint2* preP  = (uint2*)(ws + 33554432 + 16777216);           // 67,108,864 B
  f16*   WhF   = (f16*)(ws + 117440512);                       //    262,144 B
  f16*   RT    = (f16*)(ws + 117440512 + 262144);              //     65,536 B
  float* pooled= (float*)(ws + 117440512 + 262144 + 65536);    //    262,144 B

  k_embed_convert<<<8384, 256, 0, stream>>>(ids, emb, Wg, Rg, x, WhF, RT);

  // layer 0
  k_gemmln<<<1024, 256, 0, stream>>>(x, WhF, ln_w, ln_b, bg, preP);
  k_scan<0><<<512, 256, 0, stream>>>(preP, RT, gn_w, x, x, nullptr);
  // layer 1
  k_gemmln<<<1024, 256, 0, stream>>>(x, WhF + 65536, ln_w + Dn, ln_b + Dn, bg + Cn, preP);
  k_scan<1><<<512, 256, 0, stream>>>(preP, RT + 16384, gn_w + Dn, x, nullptr, pooled);

  k_head<<<512, 64, 0, stream>>>(pooled, w1, b1, w2, b2, out);
}